// Round 6
// baseline (322.625 us; speedup 1.0000x reference)
//
#include <hip/hip_runtime.h>

// CrossAttention MI355X — round 10:
//  * S-GEMM ported to 256x256 / 8-wave / 4-phase-per-K-tile (m201 regime:
//    T2-class swizzled ds_read + T3 phase interleave + T5 setprio; 128 KB LDS
//    dbuf; stage-next issued ph0/ph1, single vmcnt(0) drain at ph3 = ~600 cyc
//    issue-to-drain). Per wave: 128x64 out, 16 MFMA per phase (C-quadrant).
//  * pack_qkv: accepted at ~58 us (4 schedules all ~2.3 TB/s; negative result
//    banked). Projections / PV / out-proj unchanged (counted-vmcnt 128^2).
//
//   out = softmax(Q (K Wk + bk)^T * scale) (V Wv + bv) Wo + bo
//   softmax(S) V = (exp(S) V) / rowsum(exp(S))   (scores tiny, no max-sub)
//
// GEMM modes (D[m][n] = A[m,:]·B[n,:]^T, all operands f16):
//   0: K-proj  A=WkT(512x768)  B=kh(16384x768)   -> kpbf[kv][d]    +bk[m]
//   1: outproj A=WoT(512x512)  B=ctx(16384x512)  -> out[q][e] f32  +bo[m]
//   2: V-proj  A=WvT(512x768)  B=vh              -> vpT[b][d][kv]  +bv[m]
//   S (dedicated 256^2 kernel): A=kpbf B=qh -> P~[q][kv]=exp(scale*S), rowsum
//   4: PV      A=vpT(512x2048)  B=P~(2048x2048)  -> ctx[q][d] * 1/rowsum[q]

typedef _Float16 f16x8 __attribute__((ext_vector_type(8)));
typedef _Float16 f16x4 __attribute__((ext_vector_type(4)));
typedef float    f32x4 __attribute__((ext_vector_type(4)));

#define B_    8
#define LQ_   2048
#define LKV_  2048
#define DQ_   512
#define DC_   768

#define AS1 __attribute__((address_space(1)))
#define AS3 __attribute__((address_space(3)))

__device__ __forceinline__ void gload16(const void* g, void* l) {
    // LDS dest is wave-uniform base; HW scatters lane i -> base + i*16
    __builtin_amdgcn_global_load_lds((const AS1 void*)g, (AS3 void*)l, 16, 0, 0);
}

// ------------------------------------------------- fused weight transpose+cvt
__global__ __launch_bounds__(256) void pack_w(const float* __restrict__ Wk,
                                              const float* __restrict__ Wv,
                                              const float* __restrict__ Wo,
                                              _Float16* __restrict__ WkT,
                                              _Float16* __restrict__ WvT,
                                              _Float16* __restrict__ WoT) {
    const int NKW = DC_ * DQ_;   // 393216
    int id = blockIdx.x * 256 + threadIdx.x;
    const float* W; _Float16* WT; int off, K;
    if (id < NKW)           { W = Wk; WT = WkT; off = id;           K = DC_; }
    else if (id < 2 * NKW)  { W = Wv; WT = WvT; off = id - NKW;     K = DC_; }
    else                    { W = Wo; WT = WoT; off = id - 2 * NKW; K = DQ_; }
    int k = off / DQ_, n = off - k * DQ_;
    WT[(size_t)n * K + k] = (_Float16)W[off];
}

// ------------------------------------------------- q/k/v f32 -> f16 (one pass)
__global__ __launch_bounds__(256) void pack_qkv(const float* __restrict__ q,
                                                const float* __restrict__ k,
                                                const float* __restrict__ v,
                                                _Float16* __restrict__ qh,
                                                _Float16* __restrict__ kh,
                                                _Float16* __restrict__ vh) {
    __shared__ __align__(16) _Float16 sbuf[4096];    // 8 KB
    const int b = blockIdx.x;
    const float4* src; _Float16* dst; size_t base;   // base in float4 units
    if (b < 2048)      { src = (const float4*)q; dst = qh; base = (size_t)b * 1024; }
    else if (b < 5120) { src = (const float4*)k; dst = kh; base = (size_t)(b - 2048) * 1024; }
    else               { src = (const float4*)v; dst = vh; base = (size_t)(b - 5120) * 1024; }
    const int t = threadIdx.x;

    float4 x[4];
#pragma unroll
    for (int j = 0; j < 4; j++) x[j] = src[base + t + j * 256];

    f16x4* s4 = (f16x4*)sbuf;
#pragma unroll
    for (int j = 0; j < 4; j++) {
        f16x4 y = { (_Float16)x[j].x, (_Float16)x[j].y, (_Float16)x[j].z, (_Float16)x[j].w };
        s4[t + j * 256] = y;
    }
    __syncthreads();

    const f16x8* s8 = (const f16x8*)sbuf;
    f16x8* d8 = (f16x8*)dst;
#pragma unroll
    for (int r = 0; r < 2; r++) {
        const int idx = t + r * 256;
        d8[base / 2 + idx] = s8[idx];
    }
}

// ------------------------------------------------- S-GEMM 256x256 8-wave
// D[m=kv][n=q] = kpbf[kv,:]·qh[q,:]^T ; Pm[q][kv] = exp(scale*D), rowsum atomics.
// 512 thr = 8 waves (2M x 4N); per wave 128x64 out = 8x4 16^2 tiles, acc 128 VGPR.
// K=512, BK=64 -> 8 K-tiles; LDS dbuf 2 x (A 32K + B 32K) = 128 KB.
// Per K-tile, 4 phases (one C-quadrant each = 4m x 2n x 2ks = 16 MFMA):
//   ph0: stageA(next) | rdA(mq0) rdB(nq0) | bar | prio1 MFMA(0,0) prio0 | bar
//   ph1: stageB(next) | rdB(nq1)          | bar | prio1 MFMA(0,1) prio0 | bar
//   ph2:                rdA(mq1)          | bar | prio1 MFMA(1,1) prio0 | bar
//   ph3:                                        | prio1 MFMA(1,0) prio0 | vmcnt(0) bar
// Hazards: stage(t+1) writes buf^1, whose last readers finished at t-1's ph2
// (barrier-separated). vmcnt(0) at ph3 guarantees t+1 landed before t+1/ph0
// reads. Issue-to-drain = 3 phases (~600 cyc) hides L2/L3 latency.
__global__ __launch_bounds__(512, 2) void s_gemm8(
        const _Float16* __restrict__ A,   // kpbf [b][kv=2048][d=512]
        const _Float16* __restrict__ B,   // qh   [b][q =2048][d=512]
        float* __restrict__ rsum,
        _Float16* __restrict__ C) {       // Pm   [b][q][kv]
    constexpr int K = 512, Mn = 2048, Nn = 2048, BK = 64, NT = K / BK;
    constexpr int TB  = 256 * BK * 2;         // 32 KB per operand tile
    constexpr int STG = 2 * TB;               // 64 KB (A+B)
    __shared__ __align__(16) char smem[2 * STG];   // 128 KB

    const int lin = blockIdx.x;
    const int z = lin & 7, slot = lin >> 3;        // batch == XCD
    const int mx = slot & 7, ny = slot >> 3;       // 8 x 8 tiles
    const int m0 = mx * 256, n0 = ny * 256;

    const _Float16* Ab = A + (size_t)z * ((size_t)Mn * K);
    const _Float16* Bb = B + (size_t)z * ((size_t)Nn * K);

    const int tid = threadIdx.x, wave = tid >> 6, lane = tid & 63;
    const int l = lane & 15, quad = lane >> 4;
    const int wr = wave >> 2, wc = wave & 3;       // 2 x 4 wave grid
    const int arl = lane >> 3, apc = lane & 7;     // 8 rows x 8 chunks / instr

    f32x4 acc[8][4] = {};

    auto stageA = [&](int b, int t) {
        char* dst = smem + b * STG;
        const int k0 = t * BK;
#pragma unroll
        for (int ii = 0; ii < 4; ii++) {
            const int i = wave + ii * 8;           // 32 instrs x 8 rows = 256
            const int row = i * 8 + arl;
            gload16(Ab + (size_t)(m0 + row) * K + k0 + (apc ^ arl) * 8,
                    dst + i * 1024);
        }
    };
    auto stageB = [&](int b, int t) {
        char* dst = smem + b * STG + TB;
        const int k0 = t * BK;
#pragma unroll
        for (int ii = 0; ii < 4; ii++) {
            const int i = wave + ii * 8;
            const int row = i * 8 + arl;
            gload16(Bb + (size_t)(n0 + row) * K + k0 + (apc ^ arl) * 8,
                    dst + i * 1024);
        }
    };
    auto rdA = [&](const _Float16* As, int mq, f16x8* af) {
#pragma unroll
        for (int mt = 0; mt < 4; mt++)
#pragma unroll
            for (int ks = 0; ks < 2; ks++) {
                const int R = wr * 128 + (mq * 4 + mt) * 16 + l;
                const int cc = ks * 4 + quad;
                af[mt * 2 + ks] = *(const f16x8*)&As[R * 64 + ((cc ^ (R & 7)) * 8)];
            }
    };
    auto rdB = [&](const _Float16* Bs, int nq, f16x8* bf) {
#pragma unroll
        for (int nt = 0; nt < 2; nt++)
#pragma unroll
            for (int ks = 0; ks < 2; ks++) {
                const int R = wc * 64 + (nq * 2 + nt) * 16 + l;
                const int cc = ks * 4 + quad;
                bf[nt * 2 + ks] = *(const f16x8*)&Bs[R * 64 + ((cc ^ (R & 7)) * 8)];
            }
    };
    auto mmaQ = [&](int mq, int nq, const f16x8* af, const f16x8* bf) {
        __builtin_amdgcn_s_setprio(1);
#pragma unroll
        for (int mt = 0; mt < 4; mt++)
#pragma unroll
            for (int nt = 0; nt < 2; nt++)
#pragma unroll
                for (int ks = 0; ks < 2; ks++)
                    acc[mq * 4 + mt][nq * 2 + nt] =
                        __builtin_amdgcn_mfma_f32_16x16x32_f16(
                            af[mt * 2 + ks], bf[nt * 2 + ks],
                            acc[mq * 4 + mt][nq * 2 + nt], 0, 0, 0);
        __builtin_amdgcn_s_setprio(0);
    };

    stageA(0, 0); stageB(0, 0);
    __syncthreads();                               // tile 0 landed (vmcnt0)
    int cur = 0;
    for (int t = 0; t < NT; t++) {
        const _Float16* As = (const _Float16*)(smem + cur * STG);
        const _Float16* Bs = (const _Float16*)(smem + cur * STG + TB);
        f16x8 af[8], bf0[4], bf1[4];
        // ---- ph0
        if (t + 1 < NT) stageA(cur ^ 1, t + 1);
        rdA(As, 0, af); rdB(Bs, 0, bf0);
        __builtin_amdgcn_s_barrier();
        __builtin_amdgcn_sched_barrier(0);
        mmaQ(0, 0, af, bf0);
        __builtin_amdgcn_sched_barrier(0);
        __builtin_amdgcn_s_barrier();
        // ---- ph1
        if (t + 1 < NT) stageB(cur ^ 1, t + 1);
        rdB(Bs, 1, bf1);
        __builtin_amdgcn_s_barrier();
        __builtin_amdgcn_sched_barrier(0);
        mmaQ(0, 1, af, bf1);
        __builtin_amdgcn_sched_barrier(0);
        __builtin_amdgcn_s_barrier();
        // ---- ph2
        rdA(As, 1, af);
        __builtin_amdgcn_s_barrier();
        __builtin_amdgcn_sched_barrier(0);
        mmaQ(1, 1, af, bf1);
        __builtin_amdgcn_sched_barrier(0);
        __builtin_amdgcn_s_barrier();
        // ---- ph3
        mmaQ(1, 0, af, bf0);
        __builtin_amdgcn_sched_barrier(0);
        asm volatile("s_waitcnt vmcnt(0)" ::: "memory");
        __builtin_amdgcn_s_barrier();
        cur ^= 1;
    }
    __syncthreads();

    // ---- epilogue: exp + rowsum + coalesced store, two 128-row chunks
    constexpr int CSTR2 = 264;                     // f16 row stride (16B-mult)
    _Float16* Cs = (_Float16*)smem;
    const float scale = 0.044194173824159216f;     // 1/sqrt(512)
    float* rs = rsum + (size_t)z * Nn;
#pragma unroll
    for (int ch = 0; ch < 2; ch++) {
        if ((wc >> 1) == ch) {
#pragma unroll
            for (int nt2 = 0; nt2 < 4; nt2++) {
                const int rloc = (wc & 1) * 64 + nt2 * 16 + l;
                float srw = 0.f;
#pragma unroll
                for (int mt = 0; mt < 8; mt++) {
                    const int col = wr * 128 + mt * 16 + quad * 4;
                    f16x4 v4;
#pragma unroll
                    for (int r = 0; r < 4; r++) {
                        float e = __expf(acc[mt][nt2][r] * scale);
                        v4[r] = (_Float16)e;
                        srw += e;
                    }
                    *(f16x4*)&Cs[rloc * CSTR2 + col] = v4;
                }
                srw += __shfl_xor(srw, 16);
                srw += __shfl_xor(srw, 32);
                if (quad == 0) atomicAdd(&rs[n0 + ch * 128 + rloc], srw);
            }
        }
        __syncthreads();
        _Float16* ob = C + (size_t)z * ((size_t)Nn * Mn)
                     + (size_t)(n0 + ch * 128) * Mn + m0;
#pragma unroll
        for (int i = 0; i < 8; i++) {
            const int p = tid + i * 512;
            const int row = p >> 5, col2 = (p & 31) * 8;
            f16x8 v = *(const f16x8*)&Cs[row * CSTR2 + col2];
            *(f16x8*)(ob + (size_t)row * Mn + col2) = v;
        }
        __syncthreads();
    }
}

// ---------------------------------------------------------------- GEMM 128x128
// Double-buffered, counted-vmcnt K-loop (round-8).
template <int MODE, int GM, int GZ>
__global__ __launch_bounds__(256, 2) void gemm_db(
        const _Float16* __restrict__ A, const _Float16* __restrict__ B,
        const float* __restrict__ bias, float* __restrict__ rsum,
        void* __restrict__ C, int M, int N, int K,
        long sAb, long sBb, long sCb) {
    constexpr int BK = 64;
    constexpr int ABYTES = 128 * BK * 2;                 // 16 KB f16
    constexpr int STAGE  = 2 * ABYTES;                   // 32 KB (A+B)
    constexpr int CSTR   = 136;                          // halfs (16B-aligned rows)
    constexpr int CBYTES = (MODE == 1) ? 64 * 132 * 4 : 128 * CSTR * 2;
    constexpr int DBUF   = 2 * STAGE;                    // 64 KB
    constexpr int SMEM   = DBUF > CBYTES ? DBUF : CBYTES;
    __shared__ __align__(16) char smem[SMEM];

    const int lin = blockIdx.x;
    const int xcd = lin & 7, slot = lin >> 3;
    int mx, ny, z;
    if (GZ == 8) { z = xcd; mx = slot % GM; ny = slot / GM; }
    else         { z = 0;   mx = slot % GM; ny = (slot / GM) * 8 + xcd; }
    const int m0 = mx * 128, n0 = ny * 128;

    const _Float16* Ab = A + (size_t)z * sAb;
    const _Float16* Bb = B + (size_t)z * sBb;
    const int tid = threadIdx.x, wave = tid >> 6, lane = tid & 63;
    const int l = lane & 15, quad = lane >> 4;
    const int wr = wave >> 1, wc = wave & 1;
    const int arl = lane >> 3, apc = lane & 7;

    f32x4 acc[4][4] = {};

    auto stage = [&](int b, int k0) {
        char* dst = smem + b * STAGE;
#pragma unroll
        for (int ii = 0; ii < 4; ii++) {
            const int i = wave + ii * 4;
            const int row = i * 8 + arl;
            const int cc = apc ^ arl;
            gload16(Ab + (size_t)(m0 + row) * K + k0 + cc * 8, dst + i * 1024);
            gload16(Bb + (size_t)(n0 + row) * K + k0 + cc * 8, dst + ABYTES + i * 1024);
        }
    };

    auto compute = [&](int b) {
        const _Float16* As = (const _Float16*)(smem + b * STAGE);
        const _Float16* Bs = (const _Float16*)(smem + b * STAGE + ABYTES);
#pragma unroll
        for (int ks = 0; ks < 2; ks++) {
            f16x8 af[4], bf[4];
#pragma unroll
            for (int mt = 0; mt < 4; mt++) {
                const int R = wr * 64 + mt * 16 + l;
                const int cc = ks * 4 + quad;
                af[mt] = *(const f16x8*)&As[R * 64 + (cc ^ (R & 7)) * 8];
            }
#pragma unroll
            for (int nt = 0; nt < 4; nt++) {
                const int R = wc * 64 + nt * 16 + l;
                const int cc = ks * 4 + quad;
                bf[nt] = *(const f16x8*)&Bs[R * 64 + (cc ^ (R & 7)) * 8];
            }
#pragma unroll
            for (int mt = 0; mt < 4; mt++)
#pragma unroll
                for (int nt = 0; nt < 4; nt++)
                    acc[mt][nt] = __builtin_amdgcn_mfma_f32_16x16x32_f16(
                        af[mt], bf[nt], acc[mt][nt], 0, 0, 0);
        }
    };

    stage(0, 0);
    int cur = 0;
    for (int k0 = BK; k0 < K; k0 += BK) {
        stage(cur ^ 1, k0);
        asm volatile("s_waitcnt vmcnt(8)\n\ts_barrier" ::: "memory");
        compute(cur);
        asm volatile("s_barrier" ::: "memory");
        cur ^= 1;
    }
    asm volatile("s_waitcnt vmcnt(0)\n\ts_barrier" ::: "memory");
    compute(cur);
    __syncthreads();

    const float scale = 0.044194173824159216f;

    if constexpr (MODE == 1) {
        float* Cs32 = (float*)smem;
        float* outp = (float*)C;
#pragma unroll
        for (int ch = 0; ch < 2; ch++) {
            if (wc == ch) {
#pragma unroll
                for (int nt = 0; nt < 4; nt++) {
                    const int row = nt * 16 + l;
#pragma unroll
                    for (int mt = 0; mt < 4; mt++) {
                        const int col = wr * 64 + mt * 16 + quad * 4;
                        const float4 bv = *(const float4*)(bias + m0 + col);
                        f32x4 v = { acc[mt][nt][0] + bv.x, acc[mt][nt][1] + bv.y,
                                    acc[mt][nt][2] + bv.z, acc[mt][nt][3] + bv.w };
                        *(f32x4*)&Cs32[row * 132 + col] = v;
                    }
                }
            }
            __syncthreads();
#pragma unroll
            for (int i = 0; i < 8; i++) {
                const int p = tid + i * 256;
                const int row = p >> 5, col = (p & 31) * 4;
                f32x4 v = *(const f32x4*)&Cs32[row * 132 + col];
                *(f32x4*)(outp + (size_t)(n0 + ch * 64 + row) * M + m0 + col) = v;
            }
            __syncthreads();
        }
        return;
    } else {
        _Float16* Cs = (_Float16*)smem;
        if constexpr (MODE == 2) {
#pragma unroll
            for (int mt = 0; mt < 4; mt++) {
                const int cb = wr * 64 + mt * 16 + quad * 4;
                const float4 bv = *(const float4*)(bias + m0 + cb);
#pragma unroll
                for (int nt = 0; nt < 4; nt++) {
                    const int cn = wc * 64 + nt * 16 + l;
#pragma unroll
                    for (int r = 0; r < 4; r++)
                        Cs[(cb + r) * CSTR + cn] =
                            (_Float16)(acc[mt][nt][r] + ((const float*)&bv)[r]);
                }
            }
        } else {
            float* rs = (MODE >= 3) ? rsum + (size_t)z * N : nullptr;
#pragma unroll
            for (int nt = 0; nt < 4; nt++) {
                const int row = wc * 64 + nt * 16 + l;
                float inv = 0.f;
                if (MODE == 4) inv = 1.0f / rs[n0 + row];
#pragma unroll
                for (int mt = 0; mt < 4; mt++) {
                    const int col = wr * 64 + mt * 16 + quad * 4;
                    f16x4 v4;
                    if constexpr (MODE == 0) {
                        const float4 bv = *(const float4*)(bias + m0 + col);
#pragma unroll
                        for (int r = 0; r < 4; r++)
                            v4[r] = (_Float16)(acc[mt][nt][r] + ((const float*)&bv)[r]);
                    } else {
#pragma unroll
                        for (int r = 0; r < 4; r++)
                            v4[r] = (_Float16)(acc[mt][nt][r] * inv);
                    }
                    *(f16x4*)&Cs[row * CSTR + col] = v4;
                }
            }
        }
        __syncthreads();

        _Float16* ob;
        int ostride;
        if constexpr (MODE == 2) {
            const int bb = n0 >> 11, kv0 = n0 & 2047;
            ob = (_Float16*)C + ((size_t)bb * DQ_ + m0) * LKV_ + kv0;
            ostride = LKV_;
        } else {
            ob = (_Float16*)C + (MODE >= 3 ? (size_t)z * sCb : 0) + (size_t)n0 * M + m0;
            ostride = M;
        }
#pragma unroll
        for (int i = 0; i < 8; i++) {
            const int p = tid + i * 256;
            const int row = p >> 4, col = (p & 15) * 8;
            f16x8 v = *(const f16x8*)&Cs[row * CSTR + col];
            *(f16x8*)(ob + (size_t)row * ostride + col) = v;
        }
    }
}

// ---------------------------------------------------------------- launch
extern "C" void kernel_launch(void* const* d_in, const int* in_sizes, int n_in,
                              void* d_out, int out_size, void* d_ws, size_t ws_size,
                              hipStream_t stream) {
    const float* query = (const float*)d_in[0];
    const float* key   = (const float*)d_in[1];
    const float* value = (const float*)d_in[2];
    const float* Wk    = (const float*)d_in[3];
    const float* bk    = (const float*)d_in[4];
    const float* Wv    = (const float*)d_in[5];
    const float* bv    = (const float*)d_in[6];
    const float* Wo    = (const float*)d_in[7];
    const float* bo    = (const float*)d_in[8];
    float* out = (float*)d_out;

    const size_t NQ = (size_t)B_ * LQ_ * DQ_;    // 8,388,608
    const size_t NK = (size_t)B_ * LKV_ * DC_;   // 12,582,912

    _Float16* p    = (_Float16*)d_ws;
    _Float16* kpbf = p;  p += NQ;                  // kpbf[b][kv][d]; later reused as ctx
    _Float16* vpT  = p;  p += NQ;                  // vpT[b][d][kv]
    _Float16* WkT  = p;  p += (size_t)DC_ * DQ_;
    _Float16* WvT  = p;  p += (size_t)DC_ * DQ_;
    _Float16* WoT  = p;  p += (size_t)DQ_ * DQ_;
    float*    rowsum = (float*)p;  p += 2 * (size_t)B_ * LQ_;   // 64 KB
    _Float16* qh   = p;  p += NQ;                  // query f16, 16 MB
    _Float16* Pm   = p;  p += (size_t)B_ * LQ_ * LKV_;          // 67.1 MB
    _Float16* ctx  = kpbf;   // kpbf dead after S GEMM
    // kh/vh alias Pm: both dead before S writes Pm (stream-ordered)
    _Float16* kh   = Pm;
    _Float16* vh   = Pm + NK;

    hipMemsetAsync(rowsum, 0, (size_t)B_ * LQ_ * 4, stream);
    pack_w<<<dim3((2 * DC_ * DQ_ + DQ_ * DQ_) / 256), 256, 0, stream>>>(
        Wk, Wv, Wo, WkT, WvT, WoT);
    pack_qkv<<<dim3(8192), 256, 0, stream>>>(query, key, value, qh, kh, vh);

    // K-proj: D[d][kv] -> kpbf[kv][d]. M=512, N=16384, K=768
    gemm_db<0, 4, 1><<<dim3(512), 256, 0, stream>>>(
        WkT, kh, bk, nullptr, kpbf, 512, 16384, DC_, 0, 0, 0);
    // V-proj: D[d][kv] -> vpT[b][d][kv]
    gemm_db<2, 4, 1><<<dim3(512), 256, 0, stream>>>(
        WvT, vh, bv, nullptr, vpT, 512, 16384, DC_, 0, 0, 0);
    // S (256^2 8-wave): D[kv][q] -> P~[q][kv] = exp(scale*S) + rowsum
    s_gemm8<<<dim3(512), 512, 0, stream>>>(kpbf, qh, rowsum, Pm);
    // PV: D[d][q] -> ctx[q][d] / rowsum[q]. M=512, N=2048, K=2048
    gemm_db<4, 4, 8><<<dim3(512), 256, 0, stream>>>(
        vpT, Pm, nullptr, rowsum, ctx, DQ_, LQ_, LKV_,
        (long)DQ_ * LKV_, (long)LQ_ * LKV_, (long)LQ_ * DQ_);
    // out-proj: D[e][q] -> out[q][e] f32. M=512, N=16384, K=512
    gemm_db<1, 4, 1><<<dim3(512), 256, 0, stream>>>(
        WoT, ctx, bo, nullptr, out, 512, 16384, DQ_, 0, 0, 0);
}

// Round 7
// 319.155 us; speedup vs baseline: 1.0109x; 1.0109x over previous
//
#include <hip/hip_runtime.h>

// CrossAttention MI355X — round 11:
//  * PV + out-projection FUSED (pvo): block = 64 q x 512 d ctx tile; PV
//    K-loop (BK=64, counted vmcnt, dbuf 144 KB) -> ctx/rowsum -> LDS
//    (XOR-swizzled 16B granules) -> out-GEMM vs Wo staged in 32 KB dbuf
//    chunks -> direct f32x4 stores. Eliminates ctx HBM round-trip (33.6 MB)
//    + the entire out-proj kernel's fixed costs. batch==XCD keeps vpT (2 MB)
//    and Wo (0.5 MB) L2-resident.
//  * pack_w folded into pack_qkv (one launch, blocks >= 4096).
//  * S reverted to r4's 128^2 counted-vmcnt gemm_db (r6's 256^2 4-phase was
//    neutral; two probes, two nulls — S schedule is not the lever).
//
//   out = softmax(Q (K Wk + bk)^T * scale) (V Wv + bv) Wo + bo
//   softmax(S) V = (exp(S) V) / rowsum(exp(S))   (scores tiny, no max-sub)
//
// GEMM modes (D[m][n] = A[m,:]·B[n,:]^T, all operands f16):
//   0: K-proj  A=WkT(512x768)  B=kh(16384x768)   -> kpbf[kv][d]    +bk[m]
//   2: V-proj  A=WvT(512x768)  B=vh              -> vpT[b][d][kv]  +bv[m]
//   3: S       A=kpbf(2048x512) B=qh(2048x512)   -> P~[q][kv]=exp(scale*S), rowsum atomics
//   pvo:       ctx[q][d] = (P~·vpT^T)/rowsum ; out[q][e] = ctx·WoT^T + bo

typedef _Float16 f16x8 __attribute__((ext_vector_type(8)));
typedef _Float16 f16x4 __attribute__((ext_vector_type(4)));
typedef float    f32x4 __attribute__((ext_vector_type(4)));

#define B_    8
#define LQ_   2048
#define LKV_  2048
#define DQ_   512
#define DC_   768

#define AS1 __attribute__((address_space(1)))
#define AS3 __attribute__((address_space(3)))

__device__ __forceinline__ void gload16(const void* g, void* l) {
    // LDS dest is wave-uniform base; HW scatters lane i -> base + i*16
    __builtin_amdgcn_global_load_lds((const AS1 void*)g, (AS3 void*)l, 16, 0, 0);
}

// ------------------------------------------------- pack: q/k/v cvt + W^T cvt
// blocks [0,1024) q, [1024,2560) k, [2560,4096) v: 2048 contiguous float4
// each, 8 unit-stride dwordx4 in flight -> 8B/lane f16 stores (r4 scheme).
// blocks [4096,8192): weight transpose+cvt (old pack_w, 1 elem/thread).
__global__ __launch_bounds__(256) void pack_all(
        const float* __restrict__ q, const float* __restrict__ k,
        const float* __restrict__ v, _Float16* __restrict__ qh,
        _Float16* __restrict__ kh, _Float16* __restrict__ vh,
        const float* __restrict__ Wk, const float* __restrict__ Wv,
        const float* __restrict__ Wo, _Float16* __restrict__ WkT,
        _Float16* __restrict__ WvT, _Float16* __restrict__ WoT) {
    const int b = blockIdx.x;
    if (b >= 4096) {
        const int NKW = DC_ * DQ_;   // 393216
        int id = (b - 4096) * 256 + threadIdx.x;
        const float* W; _Float16* WT; int off, K;
        if (id < NKW)           { W = Wk; WT = WkT; off = id;           K = DC_; }
        else if (id < 2 * NKW)  { W = Wv; WT = WvT; off = id - NKW;     K = DC_; }
        else                    { W = Wo; WT = WoT; off = id - 2 * NKW; K = DQ_; }
        int kk = off / DQ_, n = off - kk * DQ_;
        WT[(size_t)n * K + kk] = (_Float16)W[off];
        return;
    }
    const float4* src; _Float16* dst; size_t base;
    if (b < 1024)      { src = (const float4*)q; dst = qh; base = (size_t)b * 2048; }
    else if (b < 2560) { src = (const float4*)k; dst = kh; base = (size_t)(b - 1024) * 2048; }
    else               { src = (const float4*)v; dst = vh; base = (size_t)(b - 2560) * 2048; }
    const size_t t = base + threadIdx.x;
    float4 x[8];
#pragma unroll
    for (int j = 0; j < 8; j++) x[j] = src[t + j * 256];
#pragma unroll
    for (int j = 0; j < 8; j++) {
        f16x4 y = { (_Float16)x[j].x, (_Float16)x[j].y, (_Float16)x[j].z, (_Float16)x[j].w };
        *(f16x4*)(dst + 4 * (t + j * 256)) = y;
    }
}

// ---------------------------------------------------------------- GEMM 128x128
// Double-buffered, counted-vmcnt K-loop (r8 structure, unchanged).
template <int MODE, int GM, int GZ>
__global__ __launch_bounds__(256, 2) void gemm_db(
        const _Float16* __restrict__ A, const _Float16* __restrict__ B,
        const float* __restrict__ bias, float* __restrict__ rsum,
        void* __restrict__ C, int M, int N, int K,
        long sAb, long sBb, long sCb) {
    constexpr int BK = 64;
    constexpr int ABYTES = 128 * BK * 2;                 // 16 KB f16
    constexpr int STAGE  = 2 * ABYTES;                   // 32 KB (A+B)
    constexpr int CSTR   = 136;                          // halfs (16B-aligned rows)
    constexpr int CBYTES = 128 * CSTR * 2;
    constexpr int DBUF   = 2 * STAGE;                    // 64 KB
    constexpr int SMEM   = DBUF > CBYTES ? DBUF : CBYTES;
    __shared__ __align__(16) char smem[SMEM];

    const int lin = blockIdx.x;
    const int xcd = lin & 7, slot = lin >> 3;
    int mx, ny, z;
    if (GZ == 8) { z = xcd; mx = slot % GM; ny = slot / GM; }
    else         { z = 0;   mx = slot % GM; ny = (slot / GM) * 8 + xcd; }
    const int m0 = mx * 128, n0 = ny * 128;

    const _Float16* Ab = A + (size_t)z * sAb;
    const _Float16* Bb = B + (size_t)z * sBb;
    const int tid = threadIdx.x, wave = tid >> 6, lane = tid & 63;
    const int l = lane & 15, quad = lane >> 4;
    const int wr = wave >> 1, wc = wave & 1;
    const int arl = lane >> 3, apc = lane & 7;

    f32x4 acc[4][4] = {};

    auto stage = [&](int b, int k0) {
        char* dst = smem + b * STAGE;
#pragma unroll
        for (int ii = 0; ii < 4; ii++) {
            const int i = wave + ii * 4;
            const int row = i * 8 + arl;
            const int cc = apc ^ arl;
            gload16(Ab + (size_t)(m0 + row) * K + k0 + cc * 8, dst + i * 1024);
            gload16(Bb + (size_t)(n0 + row) * K + k0 + cc * 8, dst + ABYTES + i * 1024);
        }
    };

    auto compute = [&](int b) {
        const _Float16* As = (const _Float16*)(smem + b * STAGE);
        const _Float16* Bs = (const _Float16*)(smem + b * STAGE + ABYTES);
#pragma unroll
        for (int ks = 0; ks < 2; ks++) {
            f16x8 af[4], bf[4];
#pragma unroll
            for (int mt = 0; mt < 4; mt++) {
                const int R = wr * 64 + mt * 16 + l;
                const int cc = ks * 4 + quad;
                af[mt] = *(const f16x8*)&As[R * 64 + (cc ^ (R & 7)) * 8];
            }
#pragma unroll
            for (int nt = 0; nt < 4; nt++) {
                const int R = wc * 64 + nt * 16 + l;
                const int cc = ks * 4 + quad;
                bf[nt] = *(const f16x8*)&Bs[R * 64 + (cc ^ (R & 7)) * 8];
            }
#pragma unroll
            for (int mt = 0; mt < 4; mt++)
#pragma unroll
                for (int nt = 0; nt < 4; nt++)
                    acc[mt][nt] = __builtin_amdgcn_mfma_f32_16x16x32_f16(
                        af[mt], bf[nt], acc[mt][nt], 0, 0, 0);
        }
    };

    stage(0, 0);
    int cur = 0;
    for (int k0 = BK; k0 < K; k0 += BK) {
        stage(cur ^ 1, k0);
        asm volatile("s_waitcnt vmcnt(8)\n\ts_barrier" ::: "memory");
        compute(cur);
        asm volatile("s_barrier" ::: "memory");
        cur ^= 1;
    }
    asm volatile("s_waitcnt vmcnt(0)\n\ts_barrier" ::: "memory");
    compute(cur);
    __syncthreads();

    // ---------------- epilogue: acc -> LDS bounce -> coalesced wide stores
    const float scale = 0.044194173824159216f;   // 1/sqrt(512)
    _Float16* Cs = (_Float16*)smem;
    if constexpr (MODE == 2) {
        // Cs[m][n] (output row = d = m)
#pragma unroll
        for (int mt = 0; mt < 4; mt++) {
            const int cb = wr * 64 + mt * 16 + quad * 4;
            const float4 bv = *(const float4*)(bias + m0 + cb);
#pragma unroll
            for (int nt = 0; nt < 4; nt++) {
                const int cn = wc * 64 + nt * 16 + l;
#pragma unroll
                for (int r = 0; r < 4; r++)
                    Cs[(cb + r) * CSTR + cn] =
                        (_Float16)(acc[mt][nt][r] + ((const float*)&bv)[r]);
            }
        }
    } else {
        // Cs[n][m] (output row = n)
        float* rs = (MODE == 3) ? rsum + (size_t)z * N : nullptr;
#pragma unroll
        for (int nt = 0; nt < 4; nt++) {
            const int row = wc * 64 + nt * 16 + l;
            float srw = 0.f;
#pragma unroll
            for (int mt = 0; mt < 4; mt++) {
                const int col = wr * 64 + mt * 16 + quad * 4;
                f16x4 v4;
                if constexpr (MODE == 0) {
                    const float4 bv = *(const float4*)(bias + m0 + col);
#pragma unroll
                    for (int r = 0; r < 4; r++)
                        v4[r] = (_Float16)(acc[mt][nt][r] + ((const float*)&bv)[r]);
                } else {
#pragma unroll
                    for (int r = 0; r < 4; r++) {
                        float e = __expf(acc[mt][nt][r] * scale);
                        v4[r] = (_Float16)e;
                        srw += e;
                    }
                }
                *(f16x4*)&Cs[row * CSTR + col] = v4;
            }
            if constexpr (MODE == 3) {
                srw += __shfl_xor(srw, 16);
                srw += __shfl_xor(srw, 32);
                if (quad == 0) atomicAdd(&rs[n0 + row], srw);
            }
        }
    }
    __syncthreads();

    _Float16* ob;
    int ostride;
    if constexpr (MODE == 2) {
        const int bb = n0 >> 11, kv0 = n0 & 2047;
        ob = (_Float16*)C + ((size_t)bb * DQ_ + m0) * LKV_ + kv0;
        ostride = LKV_;
    } else {
        ob = (_Float16*)C + (MODE == 3 ? (size_t)z * sCb : 0) + (size_t)n0 * M + m0;
        ostride = M;
    }
#pragma unroll
    for (int i = 0; i < 8; i++) {
        const int p = tid + i * 256;
        const int row = p >> 4, col = (p & 15) * 8;
        f16x8 v = *(const f16x8*)&Cs[row * CSTR + col];
        *(f16x8*)(ob + (size_t)row * ostride + col) = v;
    }
}

// ---------------------------------------------------------------- PV + outproj
// Per block: batch z (==XCD), q-tile 64. 512 thr = 8 waves; wave w owns
// d-range (then e-range) w*64, all 64 q.
// PV:  D[m=d 512][n=q 64] = vpT[d,:kv]·Pm[q,:kv]^T over kv=2048 (BK=64,
//      counted-vmcnt dbuf 2x72 KB). acc 4x4 f32x4/wave.
// ctx: acc/rowsum -> LDS f16 [64 q][512 d], XOR-swizzle on 16B granules
//      (byte = q*1024 + ((g ^ (q&7))*16 + lo), g = d>>3).
// out: D2[m=e 512][n=q 64] = WoT[e,:d]·ctx[q,:d]^T; Wo chunks [512][32]
//      32 KB dbuf'd; direct f32x4 stores + bo.
__global__ __launch_bounds__(512, 2) void pvo(
        const _Float16* __restrict__ vpT,   // [b][512][2048]
        const _Float16* __restrict__ Pm,    // [b][2048][2048]
        const _Float16* __restrict__ WoT,   // [e 512][d 512]
        const float* __restrict__ rsum,     // [b][2048]
        const float* __restrict__ bo,       // [512]
        float* __restrict__ out) {          // [b][2048][512]
    constexpr int BK = 64, NT = LKV_ / BK;          // 32 K-steps
    constexpr int AB = 512 * BK * 2;                // 64 KB vpT tile
    constexpr int BB = 64 * BK * 2;                 // 8 KB Pm tile
    constexpr int STG = AB + BB;                    // 72 KB
    __shared__ __align__(16) char smem[2 * STG];    // 144 KB

    const int lin = blockIdx.x;
    const int z = lin & 7, slot = lin >> 3;         // 32 q-tiles
    const int q0 = slot * 64;

    const _Float16* Ab = vpT + (size_t)z * ((size_t)DQ_ * LKV_);
    const _Float16* Bb = Pm + (size_t)z * ((size_t)LQ_ * LKV_) + (size_t)q0 * LKV_;

    const int tid = threadIdx.x, wave = tid >> 6, lane = tid & 63;
    const int l = lane & 15, quad = lane >> 4;
    const int arl = lane >> 3, apc = lane & 7;

    f32x4 acc[4][4] = {};

    // A: 64 gload16 (8/wave), B: 8 (1/wave) -> 9 vm-ops/wave per K-step
    auto stage = [&](int b, int k0) {
        char* da = smem + b * STG;
#pragma unroll
        for (int ii = 0; ii < 8; ii++) {
            const int i = wave + ii * 8;            // 0..63
            const int row = i * 8 + arl;
            gload16(Ab + (size_t)row * LKV_ + k0 + ((apc ^ arl) * 8), da + i * 1024);
        }
        const int rb = wave * 8 + arl;
        gload16(Bb + (size_t)rb * LKV_ + k0 + ((apc ^ arl) * 8), da + AB + wave * 1024);
    };
    auto compute = [&](int b) {
        const _Float16* As = (const _Float16*)(smem + b * STG) + wave * 64 * 64;
        const _Float16* Bs = (const _Float16*)(smem + b * STG + AB);
#pragma unroll
        for (int ks = 0; ks < 2; ks++) {
            f16x8 af[4], bf[4];
#pragma unroll
            for (int mt = 0; mt < 4; mt++) {
                const int R = mt * 16 + l;          // (R&7) == global row &7
                const int cc = ks * 4 + quad;
                af[mt] = *(const f16x8*)&As[R * 64 + ((cc ^ (R & 7)) * 8)];
            }
#pragma unroll
            for (int nt = 0; nt < 4; nt++) {
                const int R = nt * 16 + l;
                const int cc = ks * 4 + quad;
                bf[nt] = *(const f16x8*)&Bs[R * 64 + ((cc ^ (R & 7)) * 8)];
            }
#pragma unroll
            for (int mt = 0; mt < 4; mt++)
#pragma unroll
                for (int nt = 0; nt < 4; nt++)
                    acc[mt][nt] = __builtin_amdgcn_mfma_f32_16x16x32_f16(
                        af[mt], bf[nt], acc[mt][nt], 0, 0, 0);
        }
    };

    stage(0, 0);
    int cur = 0;
    for (int t = 1; t < NT; t++) {
        stage(cur ^ 1, t * BK);
        asm volatile("s_waitcnt vmcnt(9)\n\ts_barrier" ::: "memory");
        compute(cur);
        asm volatile("s_barrier" ::: "memory");
        cur ^= 1;
    }
    asm volatile("s_waitcnt vmcnt(0)\n\ts_barrier" ::: "memory");
    compute(cur);
    __syncthreads();

    // ---- ctx = acc / rowsum -> LDS [64 q][512 d] f16 swizzled (64 KB @ 0)
    {
        const float* rs = rsum + (size_t)z * LQ_;
#pragma unroll
        for (int nt = 0; nt < 4; nt++) {
            const int qq = nt * 16 + l;
            const float inv = 1.0f / rs[q0 + qq];
#pragma unroll
            for (int mt = 0; mt < 4; mt++) {
                const int g = wave * 8 + mt * 2 + (quad >> 1);     // d>>3
                char* dst = (char*)smem + qq * 1024
                          + ((g ^ (qq & 7)) * 16 + (quad & 1) * 8);
                f16x4 v = { (_Float16)(acc[0][0][0]) };            // init shape
                v[0] = (_Float16)(acc[mt][nt][0] * inv);
                v[1] = (_Float16)(acc[mt][nt][1] * inv);
                v[2] = (_Float16)(acc[mt][nt][2] * inv);
                v[3] = (_Float16)(acc[mt][nt][3] * inv);
                *(f16x4*)dst = v;
            }
        }
    }

    // Wo chunk staging: [512 e][32 d] = 32 KB at smem + 64K + b2*32K.
    // 32 gload16 (4/wave); 4 chunk-slots/row, 2-level XOR (row ^ row>>2).
    auto stageW = [&](int b2, int dc) {
        char* dw = smem + 65536 + b2 * 32768;
        const int rl = lane >> 2, c4 = lane & 3;
#pragma unroll
        for (int ii = 0; ii < 4; ii++) {
            const int i = wave + ii * 8;            // 0..31
            const int row = i * 16 + rl;
            gload16(WoT + (size_t)row * DQ_ + dc * 32
                        + ((c4 ^ ((row ^ (row >> 2)) & 3)) * 8),
                    dw + i * 1024);
        }
    };
    f32x4 acc2[4][4] = {};
    auto computeW = [&](int b2, int dc) {
        const _Float16* Ws = (const _Float16*)(smem + 65536 + b2 * 32768);
        f16x8 af[4], bf[4];
#pragma unroll
        for (int mt = 0; mt < 4; mt++) {
            const int R = wave * 64 + mt * 16 + l;
            af[mt] = *(const f16x8*)&Ws[R * 32 + ((quad ^ ((R ^ (R >> 2)) & 3)) * 8)];
        }
#pragma unroll
        for (int nt = 0; nt < 4; nt++) {
            const int qq = nt * 16 + l;
            const int g = dc * 4 + quad;
            bf[nt] = *(const f16x8*)((const char*)smem + qq * 1024
                                     + ((g ^ (qq & 7)) * 16));
        }
#pragma unroll
        for (int mt = 0; mt < 4; mt++)
#pragma unroll
            for (int nt = 0; nt < 4; nt++)
                acc2[mt][nt] = __builtin_amdgcn_mfma_f32_16x16x32_f16(
                    af[mt], bf[nt], acc2[mt][nt], 0, 0, 0);
    };

    stageW(0, 0);
    __syncthreads();            // ctx visible to all waves; chunk 0 landed
    int c2 = 0;
    for (int dc = 1; dc < 16; dc++) {
        stageW(c2 ^ 1, dc);
        asm volatile("s_waitcnt vmcnt(4)\n\ts_barrier" ::: "memory");
        computeW(c2, dc - 1);
        asm volatile("s_barrier" ::: "memory");
        c2 ^= 1;
    }
    asm volatile("s_waitcnt vmcnt(0)\n\ts_barrier" ::: "memory");
    computeW(c2, 15);

    // ---- store out[q][e] f32 + bo (16B/lane segments, 64B per quad-group)
    float* op = out + (size_t)z * ((size_t)LQ_ * DQ_) + (size_t)q0 * DQ_;
#pragma unroll
    for (int nt = 0; nt < 4; nt++) {
        const int qq = nt * 16 + l;
#pragma unroll
        for (int mt = 0; mt < 4; mt++) {
            const int e = wave * 64 + mt * 16 + quad * 4;
            const float4 bv = *(const float4*)(bo + e);
            f32x4 v = { acc2[mt][nt][0] + bv.x, acc2[mt][nt][1] + bv.y,
                        acc2[mt][nt][2] + bv.z, acc2[mt][nt][3] + bv.w };
            *(f32x4*)(op + (size_t)qq * DQ_ + e) = v;
        }
    }
}

// ---------------------------------------------------------------- launch
extern "C" void kernel_launch(void* const* d_in, const int* in_sizes, int n_in,
                              void* d_out, int out_size, void* d_ws, size_t ws_size,
                              hipStream_t stream) {
    const float* query = (const float*)d_in[0];
    const float* key   = (const float*)d_in[1];
    const float* value = (const float*)d_in[2];
    const float* Wk    = (const float*)d_in[3];
    const float* bk    = (const float*)d_in[4];
    const float* Wv    = (const float*)d_in[5];
    const float* bv    = (const float*)d_in[6];
    const float* Wo    = (const float*)d_in[7];
    const float* bo    = (const float*)d_in[8];
    float* out = (float*)d_out;

    const size_t NQ = (size_t)B_ * LQ_ * DQ_;    // 8,388,608
    const size_t NK = (size_t)B_ * LKV_ * DC_;   // 12,582,912

    _Float16* p    = (_Float16*)d_ws;
    _Float16* kpbf = p;  p += NQ;                  // kpbf[b][kv][d]
    _Float16* vpT  = p;  p += NQ;                  // vpT[b][d][kv]
    _Float16* WkT  = p;  p += (size_t)DC_ * DQ_;
    _Float16* WvT  = p;  p += (size_t)DC_ * DQ_;
    _Float16* WoT  = p;  p += (size_t)DQ_ * DQ_;
    float*    rowsum = (float*)p;  p += 2 * (size_t)B_ * LQ_;   // 64 KB
    _Float16* qh   = p;  p += NQ;                  // query f16, 16 MB
    _Float16* Pm   = p;  p += (size_t)B_ * LQ_ * LKV_;          // 67.1 MB
    // kh/vh alias Pm: both dead before S writes Pm (stream-ordered)
    _Float16* kh   = Pm;
    _Float16* vh   = Pm + NK;

    hipMemsetAsync(rowsum, 0, (size_t)B_ * LQ_ * 4, stream);
    pack_all<<<dim3(8192), 256, 0, stream>>>(
        query, key, value, qh, kh, vh, Wk, Wv, Wo, WkT, WvT, WoT);

    // K-proj: D[d][kv] -> kpbf[kv][d]. M=512, N=16384, K=768
    gemm_db<0, 4, 1><<<dim3(512), 256, 0, stream>>>(
        WkT, kh, bk, nullptr, kpbf, 512, 16384, DC_, 0, 0, 0);
    // V-proj: D[d][kv] -> vpT[b][d][kv]
    gemm_db<2, 4, 1><<<dim3(512), 256, 0, stream>>>(
        WvT, vh, bv, nullptr, vpT, 512, 16384, DC_, 0, 0, 0);
    // S: D[kv][q] -> P~[q][kv] = exp(scale*S) + rowsum. M=2048, N=2048, K=512
    gemm_db<3, 16, 8><<<dim3(2048), 256, 0, stream>>>(
        kpbf, qh, nullptr, rowsum, Pm, LKV_, LQ_, DQ_,
        (long)LKV_ * DQ_, (long)LQ_ * DQ_, (long)LQ_ * LKV_);
    // PV + out-proj fused
    pvo<<<dim3(256), 512, 0, stream>>>(vpT, Pm, WoT, rowsum, bo, out);
}